// Round 1
// 1642.852 us; speedup vs baseline: 1.0273x; 1.0273x over previous
//
#include <hip/hip_runtime.h>
#include <math.h>

#define BATCH 2
#define SEQLEN 1024
#define NTOK 2048            // BATCH*SEQLEN
#define DIN 768
#define DM 1536
#define DS 16
#define DD 96
#define EPS 1e-6f
#define NC 32                // scan chunks
#define CL 32                // chunk length (NC*CL == SEQLEN)
#define NG (BATCH*DM*DS)     // 49152 independent recurrences

typedef __attribute__((ext_vector_type(8))) short short8;
typedef __attribute__((ext_vector_type(4))) float f32x4;

static __device__ __forceinline__ unsigned short f2bf(float f) {
    unsigned int u = __float_as_uint(f);
    u += 0x7fff + ((u >> 16) & 1);           // round-to-nearest-even
    return (unsigned short)(u >> 16);
}

// ---------------- embedding gather ----------------
__global__ __launch_bounds__(192) void embed_kernel(const int* __restrict__ tok,
                                                    const float* __restrict__ emb,
                                                    float* __restrict__ seq) {
    int m = blockIdx.x;
    int t = tok[m];
    const float4* src = (const float4*)(emb + (size_t)t * DIN);
    float4* dst = (float4*)(seq + (size_t)m * DIN);
    dst[threadIdx.x] = src[threadIdx.x];
}

// ---------------- zero fill (for K-split atomic GEMM) ----------------
__global__ __launch_bounds__(256) void zero_kernel(float* __restrict__ p, int n4) {
    int i = blockIdx.x * 256 + threadIdx.x;
    if (i < n4) ((float4*)p)[i] = make_float4(0.f, 0.f, 0.f, 0.f);
}

// concat sB(16 rows) + sC(16) + sD0(96) per layer -> [4][128][DM] bf16
__global__ __launch_bounds__(256) void wcat_kernel(const float* __restrict__ sB,
                                                   const float* __restrict__ sC,
                                                   const float* __restrict__ sD0,
                                                   unsigned short* __restrict__ out) {
    int idx = blockIdx.x * 256 + threadIdx.x;       // 4*128*DM total
    int k = idx % DM;
    int row = (idx / DM) & 127;
    int layer = idx / (DM * 128);
    float v;
    if (row < 16)      v = sB[((size_t)layer * 16 + row) * DM + k];
    else if (row < 32) v = sC[((size_t)layer * 16 + (row - 16)) * DM + k];
    else               v = sD0[((size_t)layer * 96 + (row - 32)) * DM + k];
    out[idx] = f2bf(v);
}

// ---------------- rmsnorm (one block per token), bf16 out ----------------
__global__ __launch_bounds__(256) void rmsnorm_kernel(const float* __restrict__ in,
                                                      const float* __restrict__ w,
                                                      unsigned short* __restrict__ out) {
    int m = blockIdx.x;
    const float* x = in + (size_t)m * DIN;
    float v[3];
    float s = 0.f;
#pragma unroll
    for (int j = 0; j < 3; j++) {
        v[j] = x[threadIdx.x + 256 * j];
        s += v[j] * v[j];
    }
#pragma unroll
    for (int off = 32; off; off >>= 1) s += __shfl_down(s, off);
    __shared__ float wsum[4];
    int lane = threadIdx.x & 63, wv = threadIdx.x >> 6;
    if (lane == 0) wsum[wv] = s;
    __syncthreads();
    float tot = wsum[0] + wsum[1] + wsum[2] + wsum[3];
    float scale = rsqrtf(tot / (float)DIN + EPS);
#pragma unroll
    for (int j = 0; j < 3; j++) {
        int c = threadIdx.x + 256 * j;
        out[(size_t)m * DIN + c] = f2bf(v[j] * scale * w[c]);
    }
}

// ---------------- bf16 MFMA GEMM: C[M,N] = A[M,K] @ B[N,K]^T, fp32 out ----------------
// 128x128 block tile, BK=32, 4 waves, each wave 64x64 via 4x4 of 16x16x32 MFMA.
// EPI:   0 = store, 1 = C += acc (plain), 2 = atomicAdd (for K-split)
// BSRC:  0 = B is bf16 (global_load_lds), 1 = B is fp32 (reg-stage + cvt + ds_write)
// KSPLIT: blockIdx.z strides over K in K/KSPLIT chunks
// Block order is M-major (by fastest): consecutive blocks share one B panel,
// so B is fetched from HBM once instead of once per M-block wave.
template <int EPI, int BSRC, int KSPLIT>
__global__ __launch_bounds__(256) void gemm_mfma(const unsigned short* __restrict__ A,
                                                 const void* __restrict__ Bv,
                                                 float* __restrict__ C, int N, int K) {
    __shared__ unsigned short As[128 * 32];
    __shared__ unsigned short Bs[128 * 32];
    int tid = threadIdx.x;
    int lane = tid & 63, w = tid >> 6;
    int wm = w >> 1, wn = w & 1;
    int fm = lane & 15, fk = lane >> 4;

    // M-major linearized block swizzle
    int lin = blockIdx.y * gridDim.x + blockIdx.x;
    int nby = gridDim.y;
    int by = lin % nby;
    int bx = lin / nby;

    const unsigned short* Ab  = A + (size_t)by * 128 * K;
    const unsigned short* Bb16 = (const unsigned short*)Bv + (size_t)bx * 128 * K;
    const float*          Bb32 = (const float*)Bv + (size_t)bx * 128 * K;
    int r0 = tid >> 2;                // staging row (chunk id c = tid: row=c>>2)
    int ko = (tid & 3) * 8;           // 8 bf16 = 16 B per chunk
    // fp32 B: thread t loads 16 floats of row (t>>1), col half (t&1)*16
    const float* Bp = Bb32 + (size_t)(tid >> 1) * K + (tid & 1) * 16;

    int kchunk = K / KSPLIT;
    int kbeg = (KSPLIT > 1) ? blockIdx.z * kchunk : 0;
    int kend = kbeg + kchunk;

    f32x4 acc[4][4];
#pragma unroll
    for (int i = 0; i < 4; i++)
#pragma unroll
        for (int j = 0; j < 4; j++) acc[i][j] = (f32x4){0.f, 0.f, 0.f, 0.f};

    for (int k0 = kbeg; k0 < kend; k0 += 32) {
        float4 b0, b1, b2, b3;
        if (BSRC == 1) {              // issue fp32 B loads early: latency hides under barrier
            b0 = *(const float4*)(Bp + k0);
            b1 = *(const float4*)(Bp + k0 + 4);
            b2 = *(const float4*)(Bp + k0 + 8);
            b3 = *(const float4*)(Bp + k0 + 12);
        }
        __syncthreads();   // previous iter's LDS reads must finish before overwrite
#pragma unroll
        for (int j = 0; j < 2; j++) {
            int row = r0 + j * 64;
            int c = tid + j * 256;
            __builtin_amdgcn_global_load_lds(
                (const __attribute__((address_space(1))) unsigned int*)(const void*)(Ab + (size_t)row * K + k0 + ko),
                (__attribute__((address_space(3))) unsigned int*)(void*)(As + c * 8), 16, 0, 0);
            if (BSRC == 0)
                __builtin_amdgcn_global_load_lds(
                    (const __attribute__((address_space(1))) unsigned int*)(const void*)(Bb16 + (size_t)row * K + k0 + ko),
                    (__attribute__((address_space(3))) unsigned int*)(void*)(Bs + c * 8), 16, 0, 0);
        }
        if (BSRC == 1) {
            unsigned short* dst = Bs + (tid >> 1) * 32 + (tid & 1) * 16;
            short8 p0, p1;
            p0[0] = (short)f2bf(b0.x); p0[1] = (short)f2bf(b0.y);
            p0[2] = (short)f2bf(b0.z); p0[3] = (short)f2bf(b0.w);
            p0[4] = (short)f2bf(b1.x); p0[5] = (short)f2bf(b1.y);
            p0[6] = (short)f2bf(b1.z); p0[7] = (short)f2bf(b1.w);
            p1[0] = (short)f2bf(b2.x); p1[1] = (short)f2bf(b2.y);
            p1[2] = (short)f2bf(b2.z); p1[3] = (short)f2bf(b2.w);
            p1[4] = (short)f2bf(b3.x); p1[5] = (short)f2bf(b3.y);
            p1[6] = (short)f2bf(b3.z); p1[7] = (short)f2bf(b3.w);
            *(short8*)dst = p0;
            *(short8*)(dst + 8) = p1;
        }
        __syncthreads();   // drains vmcnt+lgkmcnt -> staging visible

        short8 af[4], bfv[4];
#pragma unroll
        for (int i = 0; i < 4; i++)
            af[i] = *(const short8*)(As + (wm * 64 + i * 16 + fm) * 32 + fk * 8);
#pragma unroll
        for (int j = 0; j < 4; j++)
            bfv[j] = *(const short8*)(Bs + (wn * 64 + j * 16 + fm) * 32 + fk * 8);
#pragma unroll
        for (int i = 0; i < 4; i++)
#pragma unroll
            for (int j = 0; j < 4; j++)
                acc[i][j] = __builtin_amdgcn_mfma_f32_16x16x32_bf16(af[i], bfv[j], acc[i][j], 0, 0, 0);
    }

    int rowb = by * 128 + wm * 64;
    int colb = bx * 128 + wn * 64;
#pragma unroll
    for (int i = 0; i < 4; i++)
#pragma unroll
        for (int j = 0; j < 4; j++)
#pragma unroll
            for (int r = 0; r < 4; r++) {
                int row = rowb + i * 16 + fk * 4 + r;   // C/D: col=lane&15, row=(lane>>4)*4+reg
                int col = colb + j * 16 + fm;
                size_t off = (size_t)row * N + col;
                if (EPI == 0)      C[off] = acc[i][j][r];
                else if (EPI == 1) C[off] += acc[i][j][r];
                else               unsafeAtomicAdd(&C[off], acc[i][j][r]);
            }
}

// ---------------- depthwise causal conv (K=4) + silu, fp32+bf16 out ----------------
__global__ __launch_bounds__(256) void conv_silu_kernel(const float* __restrict__ ab,
                                                        const float* __restrict__ cw,
                                                        const float* __restrict__ cb,
                                                        float* __restrict__ out,
                                                        unsigned short* __restrict__ outb) {
    int idx = blockIdx.x * 256 + threadIdx.x;   // < NTOK*DM
    int c = idx % DM;
    int t = idx / DM;
    int l = t % SEQLEN;
    float4 w4 = ((const float4*)cw)[c];
    float y = cb[c];
    y = fmaf(w4.w, ab[(size_t)t * (2 * DM) + c], y);
    if (l >= 1) y = fmaf(w4.z, ab[(size_t)(t - 1) * (2 * DM) + c], y);
    if (l >= 2) y = fmaf(w4.y, ab[(size_t)(t - 2) * (2 * DM) + c], y);
    if (l >= 3) y = fmaf(w4.x, ab[(size_t)(t - 3) * (2 * DM) + c], y);
    float sv = y / (1.f + expf(-y));
    out[(size_t)t * DM + c] = sv;
    outb[(size_t)t * DM + c] = f2bf(sv);
}

// ---------------- fp32 GEMM w/ softplus epilogue (delta), 64x64 tile ----------------
__global__ __launch_bounds__(256) void gemm32_softplus(const float* __restrict__ A, int lda,
                                                       const float* __restrict__ B,
                                                       float* __restrict__ C, int N, int K,
                                                       const float* __restrict__ bias) {
    __shared__ float As[16][68];
    __shared__ float Bs[16][68];
    int tid = threadIdx.x;
    int lr = tid >> 2;
    int lk = (tid & 3) << 2;
    const float* Aptr = A + (size_t)(blockIdx.y * 64 + lr) * lda + lk;
    const float* Bptr = B + (size_t)(blockIdx.x * 64 + lr) * K + lk;
    int tx = tid & 15, ty = tid >> 4;
    float acc[4][4] = {};
    for (int k0 = 0; k0 < K; k0 += 16) {
        float4 av = *(const float4*)(Aptr + k0);
        float4 bv = *(const float4*)(Bptr + k0);
        __syncthreads();
        As[lk + 0][lr] = av.x; As[lk + 1][lr] = av.y;
        As[lk + 2][lr] = av.z; As[lk + 3][lr] = av.w;
        Bs[lk + 0][lr] = bv.x; Bs[lk + 1][lr] = bv.y;
        Bs[lk + 2][lr] = bv.z; Bs[lk + 3][lr] = bv.w;
        __syncthreads();
#pragma unroll
        for (int kk = 0; kk < 16; kk++) {
            float4 a4 = *(const float4*)&As[kk][ty * 4];
            float4 b4 = *(const float4*)&Bs[kk][tx * 4];
            float aa[4] = {a4.x, a4.y, a4.z, a4.w};
            float bb[4] = {b4.x, b4.y, b4.z, b4.w};
#pragma unroll
            for (int i = 0; i < 4; i++)
#pragma unroll
                for (int j = 0; j < 4; j++)
                    acc[i][j] = fmaf(aa[i], bb[j], acc[i][j]);
        }
    }
    int row0 = blockIdx.y * 64 + ty * 4;
    int col0 = blockIdx.x * 64 + tx * 4;
    float4 bsv = *(const float4*)(bias + col0);
    float bb[4] = {bsv.x, bsv.y, bsv.z, bsv.w};
#pragma unroll
    for (int i = 0; i < 4; i++) {
        float* cp = C + (size_t)(row0 + i) * N + col0;
        float r[4];
#pragma unroll
        for (int j = 0; j < 4; j++) {
            float xv = acc[i][j] + bb[j];
            r[j] = fmaxf(xv, 0.f) + log1pf(expf(-fabsf(xv)));   // softplus
        }
        *(float4*)cp = make_float4(r[0], r[1], r[2], r[3]);
    }
}

// ---------------- selective scan, 3-phase chunked ----------------
// Phase 1: per (b,d,s,chunk) compute P = prod(exp(dv*A)), S = chunk-local scan end state.
__global__ __launch_bounds__(256) void scan_chunk(const float* __restrict__ delta,
                                                  const float* __restrict__ a,
                                                  const float* __restrict__ bcd,
                                                  const float* __restrict__ A_log,
                                                  float* __restrict__ P, float* __restrict__ S) {
    int bid = blockIdx.x;
    int c = bid & (NC - 1);
    int dblk = (bid >> 5) % (DM / 16);
    int b = bid / (NC * (DM / 16));
    int s = threadIdx.x & 15, dl = threadIdx.x >> 4;
    int d = dblk * 16 + dl;
    float An = -expf(A_log[d * DS + s]);
    float Pv = 1.f, Sv = 0.f;
    int t0 = b * SEQLEN + c * CL;
    for (int l = 0; l < CL; l++) {
        int t = t0 + l;
        float dv = delta[(size_t)t * DM + d];
        float av = a[(size_t)t * DM + d];
        float Bv = bcd[t * 128 + s];
        float e = expf(dv * An);
        Pv *= e;
        Sv = e * Sv + dv * Bv * av;
    }
    int g = (b * DM + d) * 16 + s;
    P[c * NG + g] = Pv;
    S[c * NG + g] = Sv;
}

// Phase 2: serial combine over the 32 chunk summaries -> h_init per chunk.
__global__ __launch_bounds__(256) void scan_combine(const float* __restrict__ P,
                                                    const float* __restrict__ S,
                                                    float* __restrict__ Hb) {
    int g = blockIdx.x * 256 + threadIdx.x;
    float h = 0.f;
#pragma unroll
    for (int c = 0; c < NC; c++) {
        Hb[c * NG + g] = h;
        h = P[c * NG + g] * h + S[c * NG + g];
    }
}

// Phase 3: re-apply with correct h_init; fuse C-reduction, D-skip, silu gate; write y fp32+bf16.
__global__ __launch_bounds__(256) void scan_apply(const float* __restrict__ delta,
                                                  const float* __restrict__ a,
                                                  const float* __restrict__ bcd,
                                                  const float* __restrict__ ab,
                                                  const float* __restrict__ A_log,
                                                  const float* __restrict__ Dp,
                                                  const float* __restrict__ Hb,
                                                  float* __restrict__ y1,
                                                  unsigned short* __restrict__ y1b) {
    int bid = blockIdx.x;
    int c = bid & (NC - 1);
    int dblk = (bid >> 5) % (DM / 16);
    int b = bid / (NC * (DM / 16));
    int s = threadIdx.x & 15, dl = threadIdx.x >> 4;
    int d = dblk * 16 + dl;
    float An = -expf(A_log[d * DS + s]);
    float Dv = Dp[d];
    int g = (b * DM + d) * 16 + s;
    float h = Hb[c * NG + g];
    int t0 = b * SEQLEN + c * CL;
    for (int l = 0; l < CL; l++) {
        int t = t0 + l;
        float dv = delta[(size_t)t * DM + d];
        float av = a[(size_t)t * DM + d];
        float Bv = bcd[t * 128 + s];
        float Cv = bcd[t * 128 + 16 + s];
        h = expf(dv * An) * h + dv * Bv * av;
        float ct = h * Cv;
        ct += __shfl_xor(ct, 1);
        ct += __shfl_xor(ct, 2);
        ct += __shfl_xor(ct, 4);
        ct += __shfl_xor(ct, 8);
        if (s == 0) {
            float bg = ab[(size_t)t * 2 * DM + DM + d];
            float sl = bg / (1.f + expf(-bg));
            float y = (ct + Dv * av) * sl;
            y1[(size_t)t * DM + d] = y;
            y1b[(size_t)t * DM + d] = f2bf(y);
        }
    }
}

extern "C" void kernel_launch(void* const* d_in, const int* in_sizes, int n_in,
                              void* d_out, int out_size, void* d_ws, size_t ws_size,
                              hipStream_t stream) {
    const int* tok        = (const int*)d_in[0];
    const float* emb      = (const float*)d_in[1];
    const float* in_proj  = (const float*)d_in[2];   // (4, 3072, 768)
    const float* out_proj = (const float*)d_in[3];   // (4, 768, 1536)
    const float* sB       = (const float*)d_in[4];   // (4, 16, 1536)
    const float* sC       = (const float*)d_in[5];   // (4, 16, 1536)
    const float* sD0      = (const float*)d_in[6];   // (4, 96, 1536)
    const float* sD1      = (const float*)d_in[7];   // (4, 1536, 96)
    const float* sD1b     = (const float*)d_in[8];   // (4, 1536)
    const float* cw       = (const float*)d_in[9];   // (4, 1536, 4)
    const float* cb       = (const float*)d_in[10];  // (4, 1536)
    const float* A_log    = (const float*)d_in[11];  // (4, 1536, 16)
    const float* Dp       = (const float*)d_in[12];  // (4, 1536)
    const float* norm_w   = (const float*)d_in[13];  // (4, 768)
    const float* norm_f   = (const float*)d_in[14];  // (768,)
    const float* head_w   = (const float*)d_in[15];  // (32000, 768)
    float* out = (float*)d_out;

    char* base = (char*)d_ws;
    float* seq   = (float*)base;          base += (size_t)NTOK * DIN * 4;
    float* ab    = (float*)base;          base += (size_t)NTOK * 2 * DM * 4;
    float* ac    = (float*)base;          base += (size_t)NTOK * DM * 4;
    float* delta = (float*)base;          base += (size_t)NTOK * DM * 4;
    float* y1    = (float*)base;          base += (size_t)NTOK * DM * 4;
    float* bcd   = (float*)base;          base += (size_t)NTOK * 128 * 4;
    unsigned short* xnb  = (unsigned short*)base;  base += (size_t)NTOK * DIN * 2;
    unsigned short* acb  = (unsigned short*)base;  base += (size_t)NTOK * DM * 2;
    unsigned short* y1b  = (unsigned short*)base;  base += (size_t)NTOK * DM * 2;
    float* P  = (float*)base;             base += (size_t)NG * NC * 4;
    float* S  = (float*)base;             base += (size_t)NG * NC * 4;
    float* Hb = (float*)base;             base += (size_t)NG * NC * 4;
    unsigned short* wcatb = (unsigned short*)base; base += (size_t)4 * 128 * DM * 2;

    embed_kernel<<<NTOK, 192, 0, stream>>>(tok, emb, seq);
    wcat_kernel<<<4 * 128 * DM / 256, 256, 0, stream>>>(sB, sC, sD0, wcatb);

    for (int i = 0; i < 4; i++) {
        rmsnorm_kernel<<<NTOK, 256, 0, stream>>>(seq, norm_w + i * DIN, xnb);
        // in_proj: B fp32 direct (no cast), M-major swizzle
        gemm_mfma<0, 1, 1><<<dim3(2 * DM / 128, NTOK / 128), 256, 0, stream>>>(
            xnb, in_proj + (size_t)i * 2 * DM * DIN, ab, 2 * DM, DIN);
        conv_silu_kernel<<<NTOK * DM / 256, 256, 0, stream>>>(
            ab, cw + (size_t)i * DM * 4, cb + (size_t)i * DM, ac, acb);
        // bcd GEMM: only 16 output blocks -> K-split x4 into zeroed buffer
        zero_kernel<<<NTOK * 128 / 4 / 256, 256, 0, stream>>>(bcd, NTOK * 128 / 4);
        gemm_mfma<2, 0, 4><<<dim3(1, NTOK / 128, 4), 256, 0, stream>>>(
            acb, wcatb + (size_t)i * 128 * DM, bcd, 128, DM);
        gemm32_softplus<<<dim3(DM / 64, NTOK / 64), 256, 0, stream>>>(
            bcd + 32, 128, sD1 + (size_t)i * DM * DD, delta, DM, DD, sD1b + (size_t)i * DM);
        scan_chunk<<<BATCH * (DM / 16) * NC, 256, 0, stream>>>(
            delta, ac, bcd, A_log + (size_t)i * DM * DS, P, S);
        scan_combine<<<NG / 256, 256, 0, stream>>>(P, S, Hb);
        scan_apply<<<BATCH * (DM / 16) * NC, 256, 0, stream>>>(
            delta, ac, bcd, ab, A_log + (size_t)i * DM * DS, Dp + (size_t)i * DM, Hb, y1, y1b);
        // out_proj residual: B fp32 direct, K-split x2, atomic accumulate into seq
        gemm_mfma<2, 1, 2><<<dim3(DIN / 128, NTOK / 128, 2), 256, 0, stream>>>(
            y1b, out_proj + (size_t)i * DIN * DM, seq, DIN, DM);
    }
    rmsnorm_kernel<<<NTOK, 256, 0, stream>>>(seq, norm_f, xnb);
    // head GEMM: B fp32 direct (kills the 147 MB head cast), M-major swizzle
    gemm_mfma<0, 1, 1><<<dim3(32000 / 128, NTOK / 128), 256, 0, stream>>>(
        xnb, head_w, out, 32000, DIN);
}

// Round 2
// 1464.830 us; speedup vs baseline: 1.1522x; 1.1215x over previous
//
#include <hip/hip_runtime.h>
#include <math.h>

#define BATCH 2
#define SEQLEN 1024
#define NTOK 2048            // BATCH*SEQLEN
#define DIN 768
#define DM 1536
#define DS 16
#define DD 96
#define EPS 1e-6f
#define NC 64                // scan chunks
#define CL 16                // chunk length (NC*CL == SEQLEN)
#define NG (BATCH*DM*DS)     // 49152 independent recurrences

typedef __attribute__((ext_vector_type(8))) short short8;
typedef __attribute__((ext_vector_type(4))) float f32x4;

static __device__ __forceinline__ unsigned short f2bf(float f) {
    unsigned int u = __float_as_uint(f);
    u += 0x7fff + ((u >> 16) & 1);           // round-to-nearest-even
    return (unsigned short)(u >> 16);
}

// ---------------- embedding gather ----------------
__global__ __launch_bounds__(192) void embed_kernel(const int* __restrict__ tok,
                                                    const float* __restrict__ emb,
                                                    float* __restrict__ seq) {
    int m = blockIdx.x;
    int t = tok[m];
    const float4* src = (const float4*)(emb + (size_t)t * DIN);
    float4* dst = (float4*)(seq + (size_t)m * DIN);
    dst[threadIdx.x] = src[threadIdx.x];
}

// ---------------- zero fill (for K-split atomic GEMM) ----------------
__global__ __launch_bounds__(256) void zero_kernel(float* __restrict__ p, int n4) {
    int i = blockIdx.x * 256 + threadIdx.x;
    if (i < n4) ((float4*)p)[i] = make_float4(0.f, 0.f, 0.f, 0.f);
}

// concat sB(16 rows) + sC(16) + sD0(96) per layer -> [4][128][DM] bf16
__global__ __launch_bounds__(256) void wcat_kernel(const float* __restrict__ sB,
                                                   const float* __restrict__ sC,
                                                   const float* __restrict__ sD0,
                                                   unsigned short* __restrict__ out) {
    int idx = blockIdx.x * 256 + threadIdx.x;       // 4*128*DM total
    int k = idx % DM;
    int row = (idx / DM) & 127;
    int layer = idx / (DM * 128);
    float v;
    if (row < 16)      v = sB[((size_t)layer * 16 + row) * DM + k];
    else if (row < 32) v = sC[((size_t)layer * 16 + (row - 16)) * DM + k];
    else               v = sD0[((size_t)layer * 96 + (row - 32)) * DM + k];
    out[idx] = f2bf(v);
}

// ---------------- rmsnorm (one block per token), bf16 out ----------------
__global__ __launch_bounds__(256) void rmsnorm_kernel(const float* __restrict__ in,
                                                      const float* __restrict__ w,
                                                      unsigned short* __restrict__ out) {
    int m = blockIdx.x;
    const float* x = in + (size_t)m * DIN;
    float v[3];
    float s = 0.f;
#pragma unroll
    for (int j = 0; j < 3; j++) {
        v[j] = x[threadIdx.x + 256 * j];
        s += v[j] * v[j];
    }
#pragma unroll
    for (int off = 32; off; off >>= 1) s += __shfl_down(s, off);
    __shared__ float wsum[4];
    int lane = threadIdx.x & 63, wv = threadIdx.x >> 6;
    if (lane == 0) wsum[wv] = s;
    __syncthreads();
    float tot = wsum[0] + wsum[1] + wsum[2] + wsum[3];
    float scale = rsqrtf(tot / (float)DIN + EPS);
#pragma unroll
    for (int j = 0; j < 3; j++) {
        int c = threadIdx.x + 256 * j;
        out[(size_t)m * DIN + c] = f2bf(v[j] * scale * w[c]);
    }
}

// ---------------- bf16 MFMA GEMM: C[M,N] = A[M,K] @ B[N,K]^T, fp32 out ----------------
// 128x128 block tile, BK=32, 4 waves, each wave 64x64 via 4x4 of 16x16x32 MFMA.
// EPI:    0 = store, 1 = C += acc, 2 = atomicAdd (K-split)
// BSRC:   0 = B bf16 via global_load_lds, 1 = B fp32 reg-staged (pipelined, swizzled ds_write)
// KSPLIT: blockIdx.z strides over K
// XCDSWZ: 1 = XCD-grouped mapping. gridDim.x must be a multiple of 8 (pad panels; blocks
//         with bx>=nbx exit). Same-XCD dispatch slots (lin%8 fixed) cover one B panel's 16
//         M-blocks consecutively -> B panel fetched by ONE XCD L2; A stays L2-resident.
template <int EPI, int BSRC, int KSPLIT, int XCDSWZ>
__global__ __launch_bounds__(256) void gemm_mfma(const unsigned short* __restrict__ A,
                                                 const void* __restrict__ Bv,
                                                 float* __restrict__ C, int N, int K, int nbx) {
    __shared__ unsigned short As[128 * 32];
    __shared__ unsigned short Bs[128 * 32];
    int tid = threadIdx.x;
    int lane = tid & 63, w = tid >> 6;
    int wm = w >> 1, wn = w & 1;
    int fm = lane & 15, fk = lane >> 4;

    int bx, by;
    if (XCDSWZ) {
        int lin = blockIdx.y * gridDim.x + blockIdx.x;   // dispatch temporal order (x fastest)
        int q = gridDim.x >> 3;                          // padded panels per XCD
        int x = lin & 7;                                 // XCD (round-robin assumption)
        int t = lin >> 3;                                // slot within XCD
        by = t % gridDim.y;                              // M fastest within a panel
        bx = x * q + t / gridDim.y;
        if (bx >= nbx) return;
    } else {
        bx = blockIdx.x; by = blockIdx.y;
    }

    const unsigned short* Ab   = A + (size_t)by * 128 * K;
    const unsigned short* Bb16 = (const unsigned short*)Bv + (size_t)bx * 128 * K;
    const float*          Bb32 = (const float*)Bv + (size_t)bx * 128 * K;
    int r0 = tid >> 2;                // A staging row
    int ko = (tid & 3) * 8;           // 8 bf16 = 16 B per chunk
    // fp32 B: thread t covers row (t>>1), 16 floats at col (t&1)*16
    const float* Bp = Bb32 + (size_t)(tid >> 1) * K + (tid & 1) * 16;

    int kchunk = K / KSPLIT;
    int kbeg = (KSPLIT > 1) ? blockIdx.z * kchunk : 0;
    int kend = kbeg + kchunk;

    f32x4 acc[4][4];
#pragma unroll
    for (int i = 0; i < 4; i++)
#pragma unroll
        for (int j = 0; j < 4; j++) acc[i][j] = (f32x4){0.f, 0.f, 0.f, 0.f};

    // swizzled Bs dest (16B chunk index d' = d ^ ((row>>1)&3)): uniform 8 lanes/bank-quad
    float4 bc0, bc1, bc2, bc3;
    unsigned short *bdst0 = nullptr, *bdst1 = nullptr;
    if (BSRC == 1) {
        int r = tid >> 1;
        int sz = (r >> 1) & 3;
        int d0 = (tid & 1) * 2;
        bdst0 = Bs + r * 32 + ((d0 + 0) ^ sz) * 8;
        bdst1 = Bs + r * 32 + ((d0 + 1) ^ sz) * 8;
        bc0 = *(const float4*)(Bp + kbeg);
        bc1 = *(const float4*)(Bp + kbeg + 4);
        bc2 = *(const float4*)(Bp + kbeg + 8);
        bc3 = *(const float4*)(Bp + kbeg + 12);
    }

    for (int k0 = kbeg; k0 < kend; k0 += 32) {
        __syncthreads();   // prev frag reads done; pipelined B loads drained here
        if (BSRC == 1) {   // convert + swizzled LDS write of current B tile
            short8 p0, p1;
            p0[0] = (short)f2bf(bc0.x); p0[1] = (short)f2bf(bc0.y);
            p0[2] = (short)f2bf(bc0.z); p0[3] = (short)f2bf(bc0.w);
            p0[4] = (short)f2bf(bc1.x); p0[5] = (short)f2bf(bc1.y);
            p0[6] = (short)f2bf(bc1.z); p0[7] = (short)f2bf(bc1.w);
            p1[0] = (short)f2bf(bc2.x); p1[1] = (short)f2bf(bc2.y);
            p1[2] = (short)f2bf(bc2.z); p1[3] = (short)f2bf(bc2.w);
            p1[4] = (short)f2bf(bc3.x); p1[5] = (short)f2bf(bc3.y);
            p1[6] = (short)f2bf(bc3.z); p1[7] = (short)f2bf(bc3.w);
            *(short8*)bdst0 = p0;
            *(short8*)bdst1 = p1;
        }
#pragma unroll
        for (int j = 0; j < 2; j++) {
            int row = r0 + j * 64;
            int c = tid + j * 256;
            __builtin_amdgcn_global_load_lds(
                (const __attribute__((address_space(1))) unsigned int*)(const void*)(Ab + (size_t)row * K + k0 + ko),
                (__attribute__((address_space(3))) unsigned int*)(void*)(As + c * 8), 16, 0, 0);
            if (BSRC == 0)
                __builtin_amdgcn_global_load_lds(
                    (const __attribute__((address_space(1))) unsigned int*)(const void*)(Bb16 + (size_t)row * K + k0 + ko),
                    (__attribute__((address_space(3))) unsigned int*)(void*)(Bs + c * 8), 16, 0, 0);
        }
        __syncthreads();   // drains A staging (+ds_write lgkm)

        if (BSRC == 1) {   // issue NEXT B tile now: in flight across frag reads + MFMA
            int kn = (k0 + 32 < kend) ? (k0 + 32) : kbeg;   // clamp: no OOB on last iter
            bc0 = *(const float4*)(Bp + kn);
            bc1 = *(const float4*)(Bp + kn + 4);
            bc2 = *(const float4*)(Bp + kn + 8);
            bc3 = *(const float4*)(Bp + kn + 12);
        }

        short8 af[4], bfv[4];
#pragma unroll
        for (int i = 0; i < 4; i++)
            af[i] = *(const short8*)(As + (wm * 64 + i * 16 + fm) * 32 + fk * 8);
#pragma unroll
        for (int j = 0; j < 4; j++) {
            int R = wn * 64 + j * 16 + fm;
            int dswz = (BSRC == 1) ? (fk ^ ((R >> 1) & 3)) : fk;
            bfv[j] = *(const short8*)(Bs + R * 32 + dswz * 8);
        }
#pragma unroll
        for (int i = 0; i < 4; i++)
#pragma unroll
            for (int j = 0; j < 4; j++)
                acc[i][j] = __builtin_amdgcn_mfma_f32_16x16x32_bf16(af[i], bfv[j], acc[i][j], 0, 0, 0);
    }

    int rowb = by * 128 + wm * 64;
    int colb = bx * 128 + wn * 64;
#pragma unroll
    for (int i = 0; i < 4; i++)
#pragma unroll
        for (int j = 0; j < 4; j++)
#pragma unroll
            for (int r = 0; r < 4; r++) {
                int row = rowb + i * 16 + fk * 4 + r;   // C/D: col=lane&15, row=(lane>>4)*4+reg
                int col = colb + j * 16 + fm;
                size_t off = (size_t)row * N + col;
                if (EPI == 0)      C[off] = acc[i][j][r];
                else if (EPI == 1) C[off] += acc[i][j][r];
                else               unsafeAtomicAdd(&C[off], acc[i][j][r]);
            }
}

// ---------------- depthwise causal conv (K=4) + silu, fp32+bf16 out ----------------
__global__ __launch_bounds__(256) void conv_silu_kernel(const float* __restrict__ ab,
                                                        const float* __restrict__ cw,
                                                        const float* __restrict__ cb,
                                                        float* __restrict__ out,
                                                        unsigned short* __restrict__ outb) {
    int idx = blockIdx.x * 256 + threadIdx.x;   // < NTOK*DM
    int c = idx % DM;
    int t = idx / DM;
    int l = t % SEQLEN;
    float4 w4 = ((const float4*)cw)[c];
    float y = cb[c];
    y = fmaf(w4.w, ab[(size_t)t * (2 * DM) + c], y);
    if (l >= 1) y = fmaf(w4.z, ab[(size_t)(t - 1) * (2 * DM) + c], y);
    if (l >= 2) y = fmaf(w4.y, ab[(size_t)(t - 2) * (2 * DM) + c], y);
    if (l >= 3) y = fmaf(w4.x, ab[(size_t)(t - 3) * (2 * DM) + c], y);
    float sv = y / (1.f + expf(-y));
    out[(size_t)t * DM + c] = sv;
    outb[(size_t)t * DM + c] = f2bf(sv);
}

// ---------------- fp32 GEMM w/ softplus epilogue (delta), 64x64 tile ----------------
__global__ __launch_bounds__(256) void gemm32_softplus(const float* __restrict__ A, int lda,
                                                       const float* __restrict__ B,
                                                       float* __restrict__ C, int N, int K,
                                                       const float* __restrict__ bias) {
    __shared__ float As[16][68];
    __shared__ float Bs[16][68];
    int tid = threadIdx.x;
    int lr = tid >> 2;
    int lk = (tid & 3) << 2;
    const float* Aptr = A + (size_t)(blockIdx.y * 64 + lr) * lda + lk;
    const float* Bptr = B + (size_t)(blockIdx.x * 64 + lr) * K + lk;
    int tx = tid & 15, ty = tid >> 4;
    float acc[4][4] = {};
    for (int k0 = 0; k0 < K; k0 += 16) {
        float4 av = *(const float4*)(Aptr + k0);
        float4 bv = *(const float4*)(Bptr + k0);
        __syncthreads();
        As[lk + 0][lr] = av.x; As[lk + 1][lr] = av.y;
        As[lk + 2][lr] = av.z; As[lk + 3][lr] = av.w;
        Bs[lk + 0][lr] = bv.x; Bs[lk + 1][lr] = bv.y;
        Bs[lk + 2][lr] = bv.z; Bs[lk + 3][lr] = bv.w;
        __syncthreads();
#pragma unroll
        for (int kk = 0; kk < 16; kk++) {
            float4 a4 = *(const float4*)&As[kk][ty * 4];
            float4 b4 = *(const float4*)&Bs[kk][tx * 4];
            float aa[4] = {a4.x, a4.y, a4.z, a4.w};
            float bb[4] = {b4.x, b4.y, b4.z, b4.w};
#pragma unroll
            for (int i = 0; i < 4; i++)
#pragma unroll
                for (int j = 0; j < 4; j++)
                    acc[i][j] = fmaf(aa[i], bb[j], acc[i][j]);
        }
    }
    int row0 = blockIdx.y * 64 + ty * 4;
    int col0 = blockIdx.x * 64 + tx * 4;
    float4 bsv = *(const float4*)(bias + col0);
    float bb[4] = {bsv.x, bsv.y, bsv.z, bsv.w};
#pragma unroll
    for (int i = 0; i < 4; i++) {
        float* cp = C + (size_t)(row0 + i) * N + col0;
        float r[4];
#pragma unroll
        for (int j = 0; j < 4; j++) {
            float xv = acc[i][j] + bb[j];
            r[j] = fmaxf(xv, 0.f) + log1pf(expf(-fabsf(xv)));   // softplus
        }
        *(float4*)cp = make_float4(r[0], r[1], r[2], r[3]);
    }
}

// ---------------- selective scan, 3-phase chunked ----------------
// Thread = (b, chunk, d); all 16 s-states live in registers.
// All global loads/stores coalesced over d; B/C broadcast from LDS.
// Phase 1: per (b,d,chunk): P[s] = prod(exp(dv*A_s)), S[s] = chunk-local end state.
__global__ __launch_bounds__(256) void scan_chunk(const float* __restrict__ delta,
                                                  const float* __restrict__ a,
                                                  const float* __restrict__ bcd,
                                                  const float* __restrict__ A_log,
                                                  float* __restrict__ P, float* __restrict__ S) {
    int tid = threadIdx.x;
    int blk = blockIdx.x;                 // BATCH * NC * (DM/256)
    int dblk = blk % (DM / 256);
    int c = (blk / (DM / 256)) % NC;
    int b = blk / ((DM / 256) * NC);
    int d = dblk * 256 + tid;
    int t0 = b * SEQLEN + c * CL;

    __shared__ float LB[CL][16];          // B part of bcd for this chunk
    {
        int row = tid >> 4, col = tid & 15;   // 256 = CL*16 values
        LB[row][col] = bcd[(size_t)(t0 + row) * 128 + col];
    }
    __syncthreads();

    float An[16];
    {
        const float4* ap = (const float4*)(A_log + (size_t)d * 16);
#pragma unroll
        for (int q = 0; q < 4; q++) {
            float4 v = ap[q];
            An[q * 4 + 0] = -expf(v.x); An[q * 4 + 1] = -expf(v.y);
            An[q * 4 + 2] = -expf(v.z); An[q * 4 + 3] = -expf(v.w);
        }
    }
    float h[16], Pv[16];
#pragma unroll
    for (int s = 0; s < 16; s++) { h[s] = 0.f; Pv[s] = 1.f; }

    for (int l = 0; l < CL; l++) {
        int t = t0 + l;
        float dv = delta[(size_t)t * DM + d];
        float av = a[(size_t)t * DM + d];
        float dva = dv * av;
#pragma unroll
        for (int s = 0; s < 16; s++) {
            float e = expf(dv * An[s]);
            Pv[s] *= e;
            h[s] = fmaf(e, h[s], dva * LB[l][s]);
        }
    }
    size_t g0 = (size_t)c * NG + (size_t)(b * DM + d) * 16;
#pragma unroll
    for (int q = 0; q < 4; q++) {
        *(f32x4*)(P + g0 + q * 4) = (f32x4){Pv[q*4], Pv[q*4+1], Pv[q*4+2], Pv[q*4+3]};
        *(f32x4*)(S + g0 + q * 4) = (f32x4){h[q*4], h[q*4+1], h[q*4+2], h[q*4+3]};
    }
}

// Phase 2: serial combine over the NC chunk summaries -> h_init per chunk.
__global__ __launch_bounds__(256) void scan_combine(const float* __restrict__ P,
                                                    const float* __restrict__ S,
                                                    float* __restrict__ Hb) {
    int g = blockIdx.x * 256 + threadIdx.x;
    float h = 0.f;
#pragma unroll
    for (int c = 0; c < NC; c++) {
        Hb[c * NG + g] = h;
        h = P[c * NG + g] * h + S[c * NG + g];
    }
}

// Phase 3: re-apply with correct h_init; fuse C-reduction (in-thread), D-skip, silu gate.
__global__ __launch_bounds__(256) void scan_apply(const float* __restrict__ delta,
                                                  const float* __restrict__ a,
                                                  const float* __restrict__ bcd,
                                                  const float* __restrict__ ab,
                                                  const float* __restrict__ A_log,
                                                  const float* __restrict__ Dp,
                                                  const float* __restrict__ Hb,
                                                  float* __restrict__ y1,
                                                  unsigned short* __restrict__ y1b) {
    int tid = threadIdx.x;
    int blk = blockIdx.x;
    int dblk = blk % (DM / 256);
    int c = (blk / (DM / 256)) % NC;
    int b = blk / ((DM / 256) * NC);
    int d = dblk * 256 + tid;
    int t0 = b * SEQLEN + c * CL;

    __shared__ float LB[CL][32];          // B (0..15) + C (16..31)
    {
        int row = tid >> 4, col = (tid & 15) * 2;   // 512 floats via float2
        *(float2*)&LB[row][col] = *(const float2*)&bcd[(size_t)(t0 + row) * 128 + col];
    }
    __syncthreads();

    float An[16];
    {
        const float4* ap = (const float4*)(A_log + (size_t)d * 16);
#pragma unroll
        for (int q = 0; q < 4; q++) {
            float4 v = ap[q];
            An[q * 4 + 0] = -expf(v.x); An[q * 4 + 1] = -expf(v.y);
            An[q * 4 + 2] = -expf(v.z); An[q * 4 + 3] = -expf(v.w);
        }
    }
    float Dv = Dp[d];
    float h[16];
    {
        const float* hp = Hb + (size_t)c * NG + (size_t)(b * DM + d) * 16;
#pragma unroll
        for (int q = 0; q < 4; q++) {
            float4 v = *(const float4*)(hp + q * 4);
            h[q * 4 + 0] = v.x; h[q * 4 + 1] = v.y; h[q * 4 + 2] = v.z; h[q * 4 + 3] = v.w;
        }
    }

    for (int l = 0; l < CL; l++) {
        int t = t0 + l;
        float dv = delta[(size_t)t * DM + d];
        float av = a[(size_t)t * DM + d];
        float dva = dv * av;
        float ct = 0.f;
#pragma unroll
        for (int s = 0; s < 16; s++) {
            float e = expf(dv * An[s]);
            h[s] = fmaf(e, h[s], dva * LB[l][s]);
            ct = fmaf(h[s], LB[l][16 + s], ct);
        }
        float bg = ab[(size_t)t * 2 * DM + DM + d];
        float sl = bg / (1.f + expf(-bg));
        float y = (ct + Dv * av) * sl;
        y1[(size_t)t * DM + d] = y;
        y1b[(size_t)t * DM + d] = f2bf(y);
    }
}

extern "C" void kernel_launch(void* const* d_in, const int* in_sizes, int n_in,
                              void* d_out, int out_size, void* d_ws, size_t ws_size,
                              hipStream_t stream) {
    const int* tok        = (const int*)d_in[0];
    const float* emb      = (const float*)d_in[1];
    const float* in_proj  = (const float*)d_in[2];   // (4, 3072, 768)
    const float* out_proj = (const float*)d_in[3];   // (4, 768, 1536)
    const float* sB       = (const float*)d_in[4];   // (4, 16, 1536)
    const float* sC       = (const float*)d_in[5];   // (4, 16, 1536)
    const float* sD0      = (const float*)d_in[6];   // (4, 96, 1536)
    const float* sD1      = (const float*)d_in[7];   // (4, 1536, 96)
    const float* sD1b     = (const float*)d_in[8];   // (4, 1536)
    const float* cw       = (const float*)d_in[9];   // (4, 1536, 4)
    const float* cb       = (const float*)d_in[10];  // (4, 1536)
    const float* A_log    = (const float*)d_in[11];  // (4, 1536, 16)
    const float* Dp       = (const float*)d_in[12];  // (4, 1536)
    const float* norm_w   = (const float*)d_in[13];  // (4, 768)
    const float* norm_f   = (const float*)d_in[14];  // (768,)
    const float* head_w   = (const float*)d_in[15];  // (32000, 768)
    float* out = (float*)d_out;

    char* base = (char*)d_ws;
    float* seq   = (float*)base;          base += (size_t)NTOK * DIN * 4;
    float* ab    = (float*)base;          base += (size_t)NTOK * 2 * DM * 4;
    float* ac    = (float*)base;          base += (size_t)NTOK * DM * 4;
    float* delta = (float*)base;          base += (size_t)NTOK * DM * 4;
    float* y1    = (float*)base;          base += (size_t)NTOK * DM * 4;
    float* bcd   = (float*)base;          base += (size_t)NTOK * 128 * 4;
    unsigned short* xnb  = (unsigned short*)base;  base += (size_t)NTOK * DIN * 2;
    unsigned short* acb  = (unsigned short*)base;  base += (size_t)NTOK * DM * 2;
    unsigned short* y1b  = (unsigned short*)base;  base += (size_t)NTOK * DM * 2;
    float* P  = (float*)base;             base += (size_t)NG * NC * 4;
    float* S  = (float*)base;             base += (size_t)NG * NC * 4;
    float* Hb = (float*)base;             base += (size_t)NG * NC * 4;
    unsigned short* wcatb = (unsigned short*)base; base += (size_t)4 * 128 * DM * 2;

    embed_kernel<<<NTOK, 192, 0, stream>>>(tok, emb, seq);
    wcat_kernel<<<4 * 128 * DM / 256, 256, 0, stream>>>(sB, sC, sD0, wcatb);

    for (int i = 0; i < 4; i++) {
        rmsnorm_kernel<<<NTOK, 256, 0, stream>>>(seq, norm_w + i * DIN, xnb);
        // in_proj: fp32 B direct, pipelined, XCD-grouped (24 panels = 3/XCD)
        gemm_mfma<0, 1, 1, 1><<<dim3(2 * DM / 128, NTOK / 128), 256, 0, stream>>>(
            xnb, in_proj + (size_t)i * 2 * DM * DIN, ab, 2 * DM, DIN, 2 * DM / 128);
        conv_silu_kernel<<<NTOK * DM / 256, 256, 0, stream>>>(
            ab, cw + (size_t)i * DM * 4, cb + (size_t)i * DM, ac, acb);
        // bcd GEMM: 16 output blocks -> K-split x4 into zeroed buffer
        zero_kernel<<<NTOK * 128 / 4 / 256, 256, 0, stream>>>(bcd, NTOK * 128 / 4);
        gemm_mfma<2, 0, 4, 0><<<dim3(1, NTOK / 128, 4), 256, 0, stream>>>(
            acb, wcatb + (size_t)i * 128 * DM, bcd, 128, DM, 1);
        gemm32_softplus<<<dim3(DM / 64, NTOK / 64), 256, 0, stream>>>(
            bcd + 32, 128, sD1 + (size_t)i * DM * DD, delta, DM, DD, sD1b + (size_t)i * DM);
        scan_chunk<<<BATCH * NC * (DM / 256), 256, 0, stream>>>(
            delta, ac, bcd, A_log + (size_t)i * DM * DS, P, S);
        scan_combine<<<NG / 256, 256, 0, stream>>>(P, S, Hb);
        scan_apply<<<BATCH * NC * (DM / 256), 256, 0, stream>>>(
            delta, ac, bcd, ab, A_log + (size_t)i * DM * DS, Dp + (size_t)i * DM, Hb, y1, y1b);
        // out_proj residual: fp32 B direct, K-split x2, atomic accumulate into seq
        gemm_mfma<2, 1, 2, 0><<<dim3(DIN / 128, NTOK / 128, 2), 256, 0, stream>>>(
            y1b, out_proj + (size_t)i * DIN * DM, seq, DIN, DM, DIN / 128);
    }
    rmsnorm_kernel<<<NTOK, 256, 0, stream>>>(seq, norm_f, xnb);
    // head GEMM: fp32 B direct, XCD-grouped (250 panels padded to 256; 32/XCD)
    gemm_mfma<0, 1, 1, 1><<<dim3(256, NTOK / 128), 256, 0, stream>>>(
        xnb, head_w, out, 32000, DIN, 32000 / 128);
}

// Round 3
// 1309.480 us; speedup vs baseline: 1.2889x; 1.1186x over previous
//
#include <hip/hip_runtime.h>
#include <math.h>

#define BATCH 2
#define SEQLEN 1024
#define NTOK 2048            // BATCH*SEQLEN
#define DIN 768
#define DM 1536
#define DS 16
#define DD 96
#define EPS 1e-6f
#define NC 64                // scan chunks
#define CL 16                // chunk length (NC*CL == SEQLEN)
#define NG (BATCH*DM*DS)     // 49152 independent recurrences

typedef __attribute__((ext_vector_type(8))) short short8;
typedef __attribute__((ext_vector_type(4))) float f32x4;

static __device__ __forceinline__ unsigned short f2bf(float f) {
    unsigned int u = __float_as_uint(f);
    u += 0x7fff + ((u >> 16) & 1);           // round-to-nearest-even
    return (unsigned short)(u >> 16);
}

// ---------------- embedding gather ----------------
__global__ __launch_bounds__(192) void embed_kernel(const int* __restrict__ tok,
                                                    const float* __restrict__ emb,
                                                    float* __restrict__ seq) {
    int m = blockIdx.x;
    int t = tok[m];
    const float4* src = (const float4*)(emb + (size_t)t * DIN);
    float4* dst = (float4*)(seq + (size_t)m * DIN);
    dst[threadIdx.x] = src[threadIdx.x];
}

// ---------------- zero fill (for K-split atomic GEMM) ----------------
__global__ __launch_bounds__(256) void zero_kernel(float* __restrict__ p, int n4) {
    int i = blockIdx.x * 256 + threadIdx.x;
    if (i < n4) ((float4*)p)[i] = make_float4(0.f, 0.f, 0.f, 0.f);
}

// ---------------- fp32 -> bf16 cast ----------------
__global__ __launch_bounds__(256) void cast_kernel(const float* __restrict__ in,
                                                   unsigned short* __restrict__ out, int n4) {
    int i = blockIdx.x * 256 + threadIdx.x;
    if (i < n4) {
        float4 v = ((const float4*)in)[i];
        ushort4 r;
        r.x = f2bf(v.x); r.y = f2bf(v.y); r.z = f2bf(v.z); r.w = f2bf(v.w);
        ((ushort4*)out)[i] = r;
    }
}

// concat sB(16 rows) + sC(16) + sD0(96) per layer -> [4][128][DM] bf16
__global__ __launch_bounds__(256) void wcat_kernel(const float* __restrict__ sB,
                                                   const float* __restrict__ sC,
                                                   const float* __restrict__ sD0,
                                                   unsigned short* __restrict__ out) {
    int idx = blockIdx.x * 256 + threadIdx.x;       // 4*128*DM total
    int k = idx % DM;
    int row = (idx / DM) & 127;
    int layer = idx / (DM * 128);
    float v;
    if (row < 16)      v = sB[((size_t)layer * 16 + row) * DM + k];
    else if (row < 32) v = sC[((size_t)layer * 16 + (row - 16)) * DM + k];
    else               v = sD0[((size_t)layer * 96 + (row - 32)) * DM + k];
    out[idx] = f2bf(v);
}

// ---------------- rmsnorm (one block per token), bf16 out ----------------
__global__ __launch_bounds__(256) void rmsnorm_kernel(const float* __restrict__ in,
                                                      const float* __restrict__ w,
                                                      unsigned short* __restrict__ out) {
    int m = blockIdx.x;
    const float* x = in + (size_t)m * DIN;
    float v[3];
    float s = 0.f;
#pragma unroll
    for (int j = 0; j < 3; j++) {
        v[j] = x[threadIdx.x + 256 * j];
        s += v[j] * v[j];
    }
#pragma unroll
    for (int off = 32; off; off >>= 1) s += __shfl_down(s, off);
    __shared__ float wsum[4];
    int lane = threadIdx.x & 63, wv = threadIdx.x >> 6;
    if (lane == 0) wsum[wv] = s;
    __syncthreads();
    float tot = wsum[0] + wsum[1] + wsum[2] + wsum[3];
    float scale = rsqrtf(tot / (float)DIN + EPS);
#pragma unroll
    for (int j = 0; j < 3; j++) {
        int c = threadIdx.x + 256 * j;
        out[(size_t)m * DIN + c] = f2bf(v[j] * scale * w[c]);
    }
}

// ---------------- bf16 MFMA GEMM: C[M,N] = A[M,K] @ B[N,K]^T, fp32 out ----------------
// 128x128 block tile, BK=64, 4 waves, each wave 64x64 via 4x4 of 16x16x32 MFMA (x2 k-steps).
// Both A and B staged bf16 via global_load_lds with both-sides XOR swizzle:
//   LDS dest linear; global source k-chunk pre-swizzled (d ^= r&7); frag read applies same XOR.
//   -> b128 frag reads are uniform 8 lanes per 4-bank group (structural minimum, conflict-free).
// EPI:    0 = store, 1 = C += acc, 2 = atomicAdd (K-split)
// XCDSWZ: 1 = XCD-grouped mapping (gridDim.x multiple of 8, pad panels; bx>=nbx exits).
//         One B panel consumed entirely within one XCD's L2; A stays L2-resident.
template <int EPI, int KSPLIT, int XCDSWZ>
__global__ __launch_bounds__(256) void gemm_mfma(const unsigned short* __restrict__ A,
                                                 const unsigned short* __restrict__ B,
                                                 float* __restrict__ C, int N, int K, int nbx) {
    __shared__ unsigned short As[128 * 64];
    __shared__ unsigned short Bs[128 * 64];
    int tid = threadIdx.x;
    int lane = tid & 63, w = tid >> 6;
    int wm = w >> 1, wn = w & 1;
    int fm = lane & 15, fk = lane >> 4;

    int bx, by;
    if (XCDSWZ) {
        int lin = blockIdx.y * gridDim.x + blockIdx.x;   // dispatch temporal order (x fastest)
        int q = gridDim.x >> 3;                          // padded panels per XCD
        int x = lin & 7;                                 // XCD (round-robin dispatch)
        int t = lin >> 3;                                // slot within XCD
        by = t % gridDim.y;                              // M fastest within a panel
        bx = x * q + t / gridDim.y;
        if (bx >= nbx) return;
    } else {
        bx = blockIdx.x; by = blockIdx.y;
    }

    const unsigned short* Ab = A + (size_t)by * 128 * K;
    const unsigned short* Bb = B + (size_t)bx * 128 * K;

    int kchunk = K / KSPLIT;
    int kbeg = (KSPLIT > 1) ? blockIdx.z * kchunk : 0;
    int kend = kbeg + kchunk;

    // staging: 1024 chunks of 16B per matrix; thread handles c = tid + j*256.
    // row r = c>>3, slot d = c&7; global source chunk = d ^ (r&7)  (involution)
    int sr[4], so[4];
#pragma unroll
    for (int j = 0; j < 4; j++) {
        int c = tid + j * 256;
        int r = c >> 3;
        sr[j] = r;
        so[j] = ((c ^ r) & 7) * 8;
    }

    f32x4 acc[4][4];
#pragma unroll
    for (int i = 0; i < 4; i++)
#pragma unroll
        for (int j = 0; j < 4; j++) acc[i][j] = (f32x4){0.f, 0.f, 0.f, 0.f};

    for (int k0 = kbeg; k0 < kend; k0 += 64) {
        __syncthreads();   // previous iter's LDS reads must finish before overwrite
#pragma unroll
        for (int j = 0; j < 4; j++) {
            int c = tid + j * 256;
            __builtin_amdgcn_global_load_lds(
                (const __attribute__((address_space(1))) unsigned int*)(const void*)(Ab + (size_t)sr[j] * K + k0 + so[j]),
                (__attribute__((address_space(3))) unsigned int*)(void*)(As + c * 8), 16, 0, 0);
            __builtin_amdgcn_global_load_lds(
                (const __attribute__((address_space(1))) unsigned int*)(const void*)(Bb + (size_t)sr[j] * K + k0 + so[j]),
                (__attribute__((address_space(3))) unsigned int*)(void*)(Bs + c * 8), 16, 0, 0);
        }
        __syncthreads();   // drains vmcnt -> staging visible

#pragma unroll
        for (int kk = 0; kk < 2; kk++) {
            short8 af[4], bfv[4];
#pragma unroll
            for (int i = 0; i < 4; i++) {
                int R = wm * 64 + i * 16 + fm;
                int dsw = (kk * 4 + fk) ^ (R & 7);
                af[i] = *(const short8*)(As + R * 64 + dsw * 8);
            }
#pragma unroll
            for (int j = 0; j < 4; j++) {
                int R = wn * 64 + j * 16 + fm;
                int dsw = (kk * 4 + fk) ^ (R & 7);
                bfv[j] = *(const short8*)(Bs + R * 64 + dsw * 8);
            }
#pragma unroll
            for (int i = 0; i < 4; i++)
#pragma unroll
                for (int j = 0; j < 4; j++)
                    acc[i][j] = __builtin_amdgcn_mfma_f32_16x16x32_bf16(af[i], bfv[j], acc[i][j], 0, 0, 0);
        }
    }

    int rowb = by * 128 + wm * 64;
    int colb = bx * 128 + wn * 64;
#pragma unroll
    for (int i = 0; i < 4; i++)
#pragma unroll
        for (int j = 0; j < 4; j++)
#pragma unroll
            for (int r = 0; r < 4; r++) {
                int row = rowb + i * 16 + fk * 4 + r;   // C/D: col=lane&15, row=(lane>>4)*4+reg
                int col = colb + j * 16 + fm;
                size_t off = (size_t)row * N + col;
                if (EPI == 0)      C[off] = acc[i][j][r];
                else if (EPI == 1) C[off] += acc[i][j][r];
                else               unsafeAtomicAdd(&C[off], acc[i][j][r]);
            }
}

// ---------------- depthwise causal conv (K=4) + silu, fp32+bf16 out ----------------
__global__ __launch_bounds__(256) void conv_silu_kernel(const float* __restrict__ ab,
                                                        const float* __restrict__ cw,
                                                        const float* __restrict__ cb,
                                                        float* __restrict__ out,
                                                        unsigned short* __restrict__ outb) {
    int idx = blockIdx.x * 256 + threadIdx.x;   // < NTOK*DM
    int c = idx % DM;
    int t = idx / DM;
    int l = t % SEQLEN;
    float4 w4 = ((const float4*)cw)[c];
    float y = cb[c];
    y = fmaf(w4.w, ab[(size_t)t * (2 * DM) + c], y);
    if (l >= 1) y = fmaf(w4.z, ab[(size_t)(t - 1) * (2 * DM) + c], y);
    if (l >= 2) y = fmaf(w4.y, ab[(size_t)(t - 2) * (2 * DM) + c], y);
    if (l >= 3) y = fmaf(w4.x, ab[(size_t)(t - 3) * (2 * DM) + c], y);
    float sv = y / (1.f + expf(-y));
    out[(size_t)t * DM + c] = sv;
    outb[(size_t)t * DM + c] = f2bf(sv);
}

// ---------------- fp32 GEMM w/ softplus epilogue (delta), 64x64 tile ----------------
__global__ __launch_bounds__(256) void gemm32_softplus(const float* __restrict__ A, int lda,
                                                       const float* __restrict__ B,
                                                       float* __restrict__ C, int N, int K,
                                                       const float* __restrict__ bias) {
    __shared__ float As[16][68];
    __shared__ float Bs[16][68];
    int tid = threadIdx.x;
    int lr = tid >> 2;
    int lk = (tid & 3) << 2;
    const float* Aptr = A + (size_t)(blockIdx.y * 64 + lr) * lda + lk;
    const float* Bptr = B + (size_t)(blockIdx.x * 64 + lr) * K + lk;
    int tx = tid & 15, ty = tid >> 4;
    float acc[4][4] = {};
    for (int k0 = 0; k0 < K; k0 += 16) {
        float4 av = *(const float4*)(Aptr + k0);
        float4 bv = *(const float4*)(Bptr + k0);
        __syncthreads();
        As[lk + 0][lr] = av.x; As[lk + 1][lr] = av.y;
        As[lk + 2][lr] = av.z; As[lk + 3][lr] = av.w;
        Bs[lk + 0][lr] = bv.x; Bs[lk + 1][lr] = bv.y;
        Bs[lk + 2][lr] = bv.z; Bs[lk + 3][lr] = bv.w;
        __syncthreads();
#pragma unroll
        for (int kk = 0; kk < 16; kk++) {
            float4 a4 = *(const float4*)&As[kk][ty * 4];
            float4 b4 = *(const float4*)&Bs[kk][tx * 4];
            float aa[4] = {a4.x, a4.y, a4.z, a4.w};
            float bb[4] = {b4.x, b4.y, b4.z, b4.w};
#pragma unroll
            for (int i = 0; i < 4; i++)
#pragma unroll
                for (int j = 0; j < 4; j++)
                    acc[i][j] = fmaf(aa[i], bb[j], acc[i][j]);
        }
    }
    int row0 = blockIdx.y * 64 + ty * 4;
    int col0 = blockIdx.x * 64 + tx * 4;
    float4 bsv = *(const float4*)(bias + col0);
    float bb[4] = {bsv.x, bsv.y, bsv.z, bsv.w};
#pragma unroll
    for (int i = 0; i < 4; i++) {
        float* cp = C + (size_t)(row0 + i) * N + col0;
        float r[4];
#pragma unroll
        for (int j = 0; j < 4; j++) {
            float xv = acc[i][j] + bb[j];
            r[j] = fmaxf(xv, 0.f) + log1pf(expf(-fabsf(xv)));   // softplus
        }
        *(float4*)cp = make_float4(r[0], r[1], r[2], r[3]);
    }
}

// ---------------- selective scan, 3-phase chunked ----------------
// Thread = (b, chunk, d); all 16 s-states live in registers.
// Phase 1: per (b,d,chunk): P[s] = prod(exp(dv*A_s)), S[s] = chunk-local end state.
__global__ __launch_bounds__(256) void scan_chunk(const float* __restrict__ delta,
                                                  const float* __restrict__ a,
                                                  const float* __restrict__ bcd,
                                                  const float* __restrict__ A_log,
                                                  float* __restrict__ P, float* __restrict__ S) {
    int tid = threadIdx.x;
    int blk = blockIdx.x;                 // BATCH * NC * (DM/256)
    int dblk = blk % (DM / 256);
    int c = (blk / (DM / 256)) % NC;
    int b = blk / ((DM / 256) * NC);
    int d = dblk * 256 + tid;
    int t0 = b * SEQLEN + c * CL;

    __shared__ float LB[CL][16];          // B part of bcd for this chunk
    {
        int row = tid >> 4, col = tid & 15;   // 256 = CL*16 values
        LB[row][col] = bcd[(size_t)(t0 + row) * 128 + col];
    }
    __syncthreads();

    float An[16];
    {
        const float4* ap = (const float4*)(A_log + (size_t)d * 16);
#pragma unroll
        for (int q = 0; q < 4; q++) {
            float4 v = ap[q];
            An[q * 4 + 0] = -expf(v.x); An[q * 4 + 1] = -expf(v.y);
            An[q * 4 + 2] = -expf(v.z); An[q * 4 + 3] = -expf(v.w);
        }
    }
    float h[16], Pv[16];
#pragma unroll
    for (int s = 0; s < 16; s++) { h[s] = 0.f; Pv[s] = 1.f; }

    for (int l = 0; l < CL; l++) {
        int t = t0 + l;
        float dv = delta[(size_t)t * DM + d];
        float av = a[(size_t)t * DM + d];
        float dva = dv * av;
#pragma unroll
        for (int s = 0; s < 16; s++) {
            float e = expf(dv * An[s]);
            Pv[s] *= e;
            h[s] = fmaf(e, h[s], dva * LB[l][s]);
        }
    }
    size_t g0 = (size_t)c * NG + (size_t)(b * DM + d) * 16;
#pragma unroll
    for (int q = 0; q < 4; q++) {
        *(f32x4*)(P + g0 + q * 4) = (f32x4){Pv[q*4], Pv[q*4+1], Pv[q*4+2], Pv[q*4+3]};
        *(f32x4*)(S + g0 + q * 4) = (f32x4){h[q*4], h[q*4+1], h[q*4+2], h[q*4+3]};
    }
}

// Phase 2: serial combine over the NC chunk summaries -> h_init per chunk.
// Hb may alias P: P[c] is read before Hb[c] is written, same thread, same address.
__global__ __launch_bounds__(256) void scan_combine(const float* __restrict__ P,
                                                    const float* __restrict__ S,
                                                    float* __restrict__ Hb) {
    int g = blockIdx.x * 256 + threadIdx.x;
    float h = 0.f;
#pragma unroll
    for (int c = 0; c < NC; c++) {
        float Pv = P[c * NG + g];
        float Sv = S[c * NG + g];
        Hb[c * NG + g] = h;
        h = fmaf(Pv, h, Sv);
    }
}

// Phase 3: re-apply with correct h_init; fuse C-reduction (in-thread), D-skip, silu gate.
__global__ __launch_bounds__(256) void scan_apply(const float* __restrict__ delta,
                                                  const float* __restrict__ a,
                                                  const float* __restrict__ bcd,
                                                  const float* __restrict__ ab,
                                                  const float* __restrict__ A_log,
                                                  const float* __restrict__ Dp,
                                                  const float* __restrict__ Hb,
                                                  unsigned short* __restrict__ y1b) {
    int tid = threadIdx.x;
    int blk = blockIdx.x;
    int dblk = blk % (DM / 256);
    int c = (blk / (DM / 256)) % NC;
    int b = blk / ((DM / 256) * NC);
    int d = dblk * 256 + tid;
    int t0 = b * SEQLEN + c * CL;

    __shared__ float LB[CL][32];          // B (0..15) + C (16..31)
    {
        int row = tid >> 4, col = (tid & 15) * 2;   // 512 floats via float2
        *(float2*)&LB[row][col] = *(const float2*)&bcd[(size_t)(t0 + row) * 128 + col];
    }
    __syncthreads();

    float An[16];
    {
        const float4* ap = (const float4*)(A_log + (size_t)d * 16);
#pragma unroll
        for (int q = 0; q < 4; q++) {
            float4 v = ap[q];
            An[q * 4 + 0] = -expf(v.x); An[q * 4 + 1] = -expf(v.y);
            An[q * 4 + 2] = -expf(v.z); An[q * 4 + 3] = -expf(v.w);
        }
    }
    float Dv = Dp[d];
    float h[16];
    {
        const float* hp = Hb + (size_t)c * NG + (size_t)(b * DM + d) * 16;
#pragma unroll
        for (int q = 0; q < 4; q++) {
            float4 v = *(const float4*)(hp + q * 4);
            h[q * 4 + 0] = v.x; h[q * 4 + 1] = v.y; h[q * 4 + 2] = v.z; h[q * 4 + 3] = v.w;
        }
    }

    for (int l = 0; l < CL; l++) {
        int t = t0 + l;
        float dv = delta[(size_t)t * DM + d];
        float av = a[(size_t)t * DM + d];
        float dva = dv * av;
        float ct = 0.f;
#pragma unroll
        for (int s = 0; s < 16; s++) {
            float e = expf(dv * An[s]);
            h[s] = fmaf(e, h[s], dva * LB[l][s]);
            ct = fmaf(h[s], LB[l][16 + s], ct);
        }
        float bg = ab[(size_t)t * 2 * DM + DM + d];
        float sl = bg / (1.f + expf(-bg));
        float y = (ct + Dv * av) * sl;
        y1b[(size_t)t * DM + d] = f2bf(y);
    }
}

extern "C" void kernel_launch(void* const* d_in, const int* in_sizes, int n_in,
                              void* d_out, int out_size, void* d_ws, size_t ws_size,
                              hipStream_t stream) {
    const int* tok        = (const int*)d_in[0];
    const float* emb      = (const float*)d_in[1];
    const float* in_proj  = (const float*)d_in[2];   // (4, 3072, 768)
    const float* out_proj = (const float*)d_in[3];   // (4, 768, 1536)
    const float* sB       = (const float*)d_in[4];   // (4, 16, 1536)
    const float* sC       = (const float*)d_in[5];   // (4, 16, 1536)
    const float* sD0      = (const float*)d_in[6];   // (4, 96, 1536)
    const float* sD1      = (const float*)d_in[7];   // (4, 1536, 96)
    const float* sD1b     = (const float*)d_in[8];   // (4, 1536)
    const float* cw       = (const float*)d_in[9];   // (4, 1536, 4)
    const float* cb       = (const float*)d_in[10];  // (4, 1536)
    const float* A_log    = (const float*)d_in[11];  // (4, 1536, 16)
    const float* Dp       = (const float*)d_in[12];  // (4, 1536)
    const float* norm_w   = (const float*)d_in[13];  // (4, 768)
    const float* norm_f   = (const float*)d_in[14];  // (768,)
    const float* head_w   = (const float*)d_in[15];  // (32000, 768)
    float* out = (float*)d_out;

    char* base = (char*)d_ws;
    float* seq   = (float*)base;          base += (size_t)NTOK * DIN * 4;
    float* ab    = (float*)base;          base += (size_t)NTOK * 2 * DM * 4;
    float* ac    = (float*)base;          base += (size_t)NTOK * DM * 4;
    float* delta = (float*)base;          base += (size_t)NTOK * DM * 4;
    float* bcd   = (float*)base;          base += (size_t)NTOK * 128 * 4;
    unsigned short* xnb  = (unsigned short*)base;  base += (size_t)NTOK * DIN * 2;
    unsigned short* acb  = (unsigned short*)base;  base += (size_t)NTOK * DM * 2;
    unsigned short* y1b  = (unsigned short*)base;  base += (size_t)NTOK * DM * 2;
    float* P  = (float*)base;             base += (size_t)NG * NC * 4;   // Hb aliases P
    float* S  = (float*)base;             base += (size_t)NG * NC * 4;
    unsigned short* inpb  = (unsigned short*)base; base += (size_t)4 * 2 * DM * DIN * 2;
    unsigned short* outpb = (unsigned short*)base; base += (size_t)4 * DIN * DM * 2;
    unsigned short* wcatb = (unsigned short*)base; base += (size_t)4 * 128 * DM * 2;
    float* Hb = P;                        // in-place combine (read-before-write per thread)
    // head bf16 weights alias the (dead-by-then) ab+ac+delta region: 49.2 MB < 50.3 MB
    unsigned short* headb = (unsigned short*)ab;

    embed_kernel<<<NTOK, 192, 0, stream>>>(tok, emb, seq);
    wcat_kernel<<<4 * 128 * DM / 256, 256, 0, stream>>>(sB, sC, sD0, wcatb);
    cast_kernel<<<(4 * 2 * DM * DIN / 4 + 255) / 256, 256, 0, stream>>>(in_proj, inpb, 4 * 2 * DM * DIN / 4);
    cast_kernel<<<(4 * DIN * DM / 4 + 255) / 256, 256, 0, stream>>>(out_proj, outpb, 4 * DIN * DM / 4);

    for (int i = 0; i < 4; i++) {
        rmsnorm_kernel<<<NTOK, 256, 0, stream>>>(seq, norm_w + i * DIN, xnb);
        // in_proj: bf16 B, XCD-grouped (24 panels = 3/XCD)
        gemm_mfma<0, 1, 1><<<dim3(2 * DM / 128, NTOK / 128), 256, 0, stream>>>(
            xnb, inpb + (size_t)i * 2 * DM * DIN, ab, 2 * DM, DIN, 2 * DM / 128);
        conv_silu_kernel<<<NTOK * DM / 256, 256, 0, stream>>>(
            ab, cw + (size_t)i * DM * 4, cb + (size_t)i * DM, ac, acb);
        // bcd GEMM: 16 output blocks -> K-split x8 into zeroed buffer (128 blocks)
        zero_kernel<<<NTOK * 128 / 4 / 256, 256, 0, stream>>>(bcd, NTOK * 128 / 4);
        gemm_mfma<2, 8, 0><<<dim3(1, NTOK / 128, 8), 256, 0, stream>>>(
            acb, wcatb + (size_t)i * 128 * DM, bcd, 128, DM, 1);
        gemm32_softplus<<<dim3(DM / 64, NTOK / 64), 256, 0, stream>>>(
            bcd + 32, 128, sD1 + (size_t)i * DM * DD, delta, DM, DD, sD1b + (size_t)i * DM);
        scan_chunk<<<BATCH * NC * (DM / 256), 256, 0, stream>>>(
            delta, ac, bcd, A_log + (size_t)i * DM * DS, P, S);
        scan_combine<<<NG / 256, 256, 0, stream>>>(P, S, Hb);
        scan_apply<<<BATCH * NC * (DM / 256), 256, 0, stream>>>(
            delta, ac, bcd, ab, A_log + (size_t)i * DM * DS, Dp + (size_t)i * DM, Hb, y1b);
        // out_proj residual: bf16 B, K-split x4 (384 blocks), atomic accumulate into seq
        gemm_mfma<2, 4, 0><<<dim3(DIN / 128, NTOK / 128, 4), 256, 0, stream>>>(
            y1b, outpb + (size_t)i * DIN * DM, seq, DIN, DM, DIN / 128);
    }
    rmsnorm_kernel<<<NTOK, 256, 0, stream>>>(seq, norm_f, xnb);
    cast_kernel<<<(32000 * DIN / 4 + 255) / 256, 256, 0, stream>>>(head_w, headb, 32000 * DIN / 4);
    // head GEMM: bf16 B, XCD-grouped (250 panels padded to 256; 32/XCD)
    gemm_mfma<0, 1, 1><<<dim3(256, NTOK / 128), 256, 0, stream>>>(
        xnb, headb, out, 32000, DIN, 32000 / 128);
}

// Round 4
// 1290.091 us; speedup vs baseline: 1.3082x; 1.0150x over previous
//
#include <hip/hip_runtime.h>
#include <math.h>

#define BATCH 2
#define SEQLEN 1024
#define NTOK 2048            // BATCH*SEQLEN
#define DIN 768
#define DM 1536
#define DS 16
#define DD 96
#define EPS 1e-6f
#define NC 64                // scan chunks
#define CL 16                // chunk length (NC*CL == SEQLEN)
#define NG (BATCH*DM*DS)     // 49152 independent recurrences

typedef __attribute__((ext_vector_type(8))) short short8;
typedef __attribute__((ext_vector_type(4))) float f32x4;

static __device__ __forceinline__ unsigned short f2bf(float f) {
    unsigned int u = __float_as_uint(f);
    u += 0x7fff + ((u >> 16) & 1);           // round-to-nearest-even
    return (unsigned short)(u >> 16);
}

// ---------------- embedding gather ----------------
__global__ __launch_bounds__(192) void embed_kernel(const int* __restrict__ tok,
                                                    const float* __restrict__ emb,
                                                    float* __restrict__ seq) {
    int m = blockIdx.x;
    int t = tok[m];
    const float4* src = (const float4*)(emb + (size_t)t * DIN);
    float4* dst = (float4*)(seq + (size_t)m * DIN);
    dst[threadIdx.x] = src[threadIdx.x];
}

// ---------------- zero fill (for K-split atomic GEMM) ----------------
__global__ __launch_bounds__(256) void zero_kernel(float* __restrict__ p, int n4) {
    int i = blockIdx.x * 256 + threadIdx.x;
    if (i < n4) ((float4*)p)[i] = make_float4(0.f, 0.f, 0.f, 0.f);
}

// ---------------- fp32 -> bf16 cast ----------------
__global__ __launch_bounds__(256) void cast_kernel(const float* __restrict__ in,
                                                   unsigned short* __restrict__ out, int n4) {
    int i = blockIdx.x * 256 + threadIdx.x;
    if (i < n4) {
        float4 v = ((const float4*)in)[i];
        ushort4 r;
        r.x = f2bf(v.x); r.y = f2bf(v.y); r.z = f2bf(v.z); r.w = f2bf(v.w);
        ((ushort4*)out)[i] = r;
    }
}

// concat sB(16 rows) + sC(16) + sD0(96) per layer -> [4][128][DM] bf16
__global__ __launch_bounds__(256) void wcat_kernel(const float* __restrict__ sB,
                                                   const float* __restrict__ sC,
                                                   const float* __restrict__ sD0,
                                                   unsigned short* __restrict__ out) {
    int idx = blockIdx.x * 256 + threadIdx.x;       // 4*128*DM total
    int k = idx % DM;
    int row = (idx / DM) & 127;
    int layer = idx / (DM * 128);
    float v;
    if (row < 16)      v = sB[((size_t)layer * 16 + row) * DM + k];
    else if (row < 32) v = sC[((size_t)layer * 16 + (row - 16)) * DM + k];
    else               v = sD0[((size_t)layer * 96 + (row - 32)) * DM + k];
    out[idx] = f2bf(v);
}

// ---------------- rmsnorm (one block per token), bf16 out ----------------
__global__ __launch_bounds__(256) void rmsnorm_kernel(const float* __restrict__ in,
                                                      const float* __restrict__ w,
                                                      unsigned short* __restrict__ out) {
    int m = blockIdx.x;
    const float* x = in + (size_t)m * DIN;
    float v[3];
    float s = 0.f;
#pragma unroll
    for (int j = 0; j < 3; j++) {
        v[j] = x[threadIdx.x + 256 * j];
        s += v[j] * v[j];
    }
#pragma unroll
    for (int off = 32; off; off >>= 1) s += __shfl_down(s, off);
    __shared__ float wsum[4];
    int lane = threadIdx.x & 63, wv = threadIdx.x >> 6;
    if (lane == 0) wsum[wv] = s;
    __syncthreads();
    float tot = wsum[0] + wsum[1] + wsum[2] + wsum[3];
    float scale = rsqrtf(tot / (float)DIN + EPS);
#pragma unroll
    for (int j = 0; j < 3; j++) {
        int c = threadIdx.x + 256 * j;
        out[(size_t)m * DIN + c] = f2bf(v[j] * scale * w[c]);
    }
}

// ---------------- bf16 MFMA GEMM: C[M,N] = A[M,K] @ B[N,K]^T, fp32 out ----------------
// 128x128 tile, BK=32, double-buffered LDS, ONE barrier per K-step (min 2-phase pipeline):
//   stage(t+1) issued BEFORE compute(t); vmcnt(0) drain at end-of-iter barrier is covered
//   by ds_read + MFMA of the current tile (~300-400 cyc). Race-safe: buf^1's last reads
//   completed before the previous barrier (all waves passed it post-MFMA).
// Swizzle (conflict-free b128 reads at 64-B rows): chunk (R,d) stored in line-pair p=R>>1
//   at slot ((R&1)*4+d) ^ (p&7). LDS dest stays linear for global_load_lds; the global
//   SOURCE applies the inverse (involution) permutation; frag reads apply the same XOR.
// EPI:    0 = store, 1 = C += acc, 2 = atomicAdd (K-split)
// XCDSWZ: 1 = XCD-grouped mapping (gridDim.x multiple of 8; bx>=nbx exits).
template <int EPI, int KSPLIT, int XCDSWZ>
__global__ __launch_bounds__(256, 4) void gemm_mfma(const unsigned short* __restrict__ A,
                                                    const unsigned short* __restrict__ B,
                                                    float* __restrict__ C, int N, int K, int nbx) {
    __shared__ unsigned short As[2][128 * 32];
    __shared__ unsigned short Bs[2][128 * 32];
    int tid = threadIdx.x;
    int lane = tid & 63, w = tid >> 6;
    int wm = w >> 1, wn = w & 1;
    int fm = lane & 15, fk = lane >> 4;

    int bx, by;
    if (XCDSWZ) {
        int lin = blockIdx.y * gridDim.x + blockIdx.x;   // dispatch temporal order (x fastest)
        int q = gridDim.x >> 3;                          // padded panels per XCD
        int x = lin & 7;                                 // XCD (round-robin dispatch)
        int t = lin >> 3;                                // slot within XCD
        by = t % gridDim.y;                              // M fastest within a panel
        bx = x * q + t / gridDim.y;
        if (bx >= nbx) return;
    } else {
        bx = blockIdx.x; by = blockIdx.y;
    }

    const unsigned short* Ab = A + (size_t)by * 128 * K;
    const unsigned short* Bb = B + (size_t)bx * 128 * K;

    int kchunk = K / KSPLIT;
    int kbeg = (KSPLIT > 1) ? blockIdx.z * kchunk : 0;
    int nt = kchunk >> 5;               // K-steps of 32

    // stage-source mapping: dest chunk c (linear, 16 B) -> (row srcR, k-chunk srcO)
    // p = c>>3, u = (c&7) ^ (p&7); srcR = 2p + (u>>2); k-chunk = u&3
    int srcR[2], srcO[2];
#pragma unroll
    for (int j = 0; j < 2; j++) {
        int c = tid + j * 256;
        int p = c >> 3;
        int u = (c & 7) ^ (p & 7);
        srcR[j] = p * 2 + (u >> 2);
        srcO[j] = (u & 3) * 8;          // shorts
    }

    // frag read offsets (shorts): addr(R) = (R>>1)*64 + ((((R&1)<<2)|fk) ^ ((R>>1)&7))*8
    int aoff[4], boff[4];
#pragma unroll
    for (int i = 0; i < 4; i++) {
        int R = wm * 64 + i * 16 + fm;
        aoff[i] = (R >> 1) * 64 + (((((R & 1) << 2) | fk) ^ ((R >> 1) & 7)) * 8);
        int Rb = wn * 64 + i * 16 + fm;
        boff[i] = (Rb >> 1) * 64 + (((((Rb & 1) << 2) | fk) ^ ((Rb >> 1) & 7)) * 8);
    }

    f32x4 acc[4][4];
#pragma unroll
    for (int i = 0; i < 4; i++)
#pragma unroll
        for (int j = 0; j < 4; j++) acc[i][j] = (f32x4){0.f, 0.f, 0.f, 0.f};

    auto STAGE = [&](int buf, int k0) {
#pragma unroll
        for (int j = 0; j < 2; j++) {
            int c = tid + j * 256;
            __builtin_amdgcn_global_load_lds(
                (const __attribute__((address_space(1))) unsigned int*)(const void*)(Ab + (size_t)srcR[j] * K + k0 + srcO[j]),
                (__attribute__((address_space(3))) unsigned int*)(void*)(&As[buf][0] + c * 8), 16, 0, 0);
            __builtin_amdgcn_global_load_lds(
                (const __attribute__((address_space(1))) unsigned int*)(const void*)(Bb + (size_t)srcR[j] * K + k0 + srcO[j]),
                (__attribute__((address_space(3))) unsigned int*)(void*)(&Bs[buf][0] + c * 8), 16, 0, 0);
        }
    };

    STAGE(0, kbeg);
    __syncthreads();                    // prologue drain
    int cur = 0;
    for (int t = 0; t < nt; ++t) {
        if (t + 1 < nt) STAGE(cur ^ 1, kbeg + (t + 1) * 32);   // next tile in flight
        short8 af[4], bfv[4];
#pragma unroll
        for (int i = 0; i < 4; i++) af[i] = *(const short8*)(&As[cur][0] + aoff[i]);
#pragma unroll
        for (int j = 0; j < 4; j++) bfv[j] = *(const short8*)(&Bs[cur][0] + boff[j]);
#pragma unroll
        for (int i = 0; i < 4; i++)
#pragma unroll
            for (int j = 0; j < 4; j++)
                acc[i][j] = __builtin_amdgcn_mfma_f32_16x16x32_bf16(af[i], bfv[j], acc[i][j], 0, 0, 0);
        __syncthreads();                // single barrier: drains next-tile loads (covered)
        cur ^= 1;
    }

    int rowb = by * 128 + wm * 64;
    int colb = bx * 128 + wn * 64;
#pragma unroll
    for (int i = 0; i < 4; i++)
#pragma unroll
        for (int j = 0; j < 4; j++)
#pragma unroll
            for (int r = 0; r < 4; r++) {
                int row = rowb + i * 16 + fk * 4 + r;   // C/D: col=lane&15, row=(lane>>4)*4+reg
                int col = colb + j * 16 + fm;
                size_t off = (size_t)row * N + col;
                if (EPI == 0)      C[off] = acc[i][j][r];
                else if (EPI == 1) C[off] += acc[i][j][r];
                else               unsafeAtomicAdd(&C[off], acc[i][j][r]);
            }
}

// ---------------- depthwise causal conv (K=4) + silu, fp32+bf16 out ----------------
__global__ __launch_bounds__(256) void conv_silu_kernel(const float* __restrict__ ab,
                                                        const float* __restrict__ cw,
                                                        const float* __restrict__ cb,
                                                        float* __restrict__ out,
                                                        unsigned short* __restrict__ outb) {
    int idx = blockIdx.x * 256 + threadIdx.x;   // < NTOK*DM
    int c = idx % DM;
    int t = idx / DM;
    int l = t % SEQLEN;
    float4 w4 = ((const float4*)cw)[c];
    float y = cb[c];
    y = fmaf(w4.w, ab[(size_t)t * (2 * DM) + c], y);
    if (l >= 1) y = fmaf(w4.z, ab[(size_t)(t - 1) * (2 * DM) + c], y);
    if (l >= 2) y = fmaf(w4.y, ab[(size_t)(t - 2) * (2 * DM) + c], y);
    if (l >= 3) y = fmaf(w4.x, ab[(size_t)(t - 3) * (2 * DM) + c], y);
    float sv = y / (1.f + expf(-y));
    out[(size_t)t * DM + c] = sv;
    outb[(size_t)t * DM + c] = f2bf(sv);
}

// ---------------- fp32 GEMM w/ softplus epilogue (delta), 64x64 tile ----------------
__global__ __launch_bounds__(256) void gemm32_softplus(const float* __restrict__ A, int lda,
                                                       const float* __restrict__ B,
                                                       float* __restrict__ C, int N, int K,
                                                       const float* __restrict__ bias) {
    __shared__ float As[16][68];
    __shared__ float Bs[16][68];
    int tid = threadIdx.x;
    int lr = tid >> 2;
    int lk = (tid & 3) << 2;
    const float* Aptr = A + (size_t)(blockIdx.y * 64 + lr) * lda + lk;
    const float* Bptr = B + (size_t)(blockIdx.x * 64 + lr) * K + lk;
    int tx = tid & 15, ty = tid >> 4;
    float acc[4][4] = {};
    for (int k0 = 0; k0 < K; k0 += 16) {
        float4 av = *(const float4*)(Aptr + k0);
        float4 bv = *(const float4*)(Bptr + k0);
        __syncthreads();
        As[lk + 0][lr] = av.x; As[lk + 1][lr] = av.y;
        As[lk + 2][lr] = av.z; As[lk + 3][lr] = av.w;
        Bs[lk + 0][lr] = bv.x; Bs[lk + 1][lr] = bv.y;
        Bs[lk + 2][lr] = bv.z; Bs[lk + 3][lr] = bv.w;
        __syncthreads();
#pragma unroll
        for (int kk = 0; kk < 16; kk++) {
            float4 a4 = *(const float4*)&As[kk][ty * 4];
            float4 b4 = *(const float4*)&Bs[kk][tx * 4];
            float aa[4] = {a4.x, a4.y, a4.z, a4.w};
            float bb[4] = {b4.x, b4.y, b4.z, b4.w};
#pragma unroll
            for (int i = 0; i < 4; i++)
#pragma unroll
                for (int j = 0; j < 4; j++)
                    acc[i][j] = fmaf(aa[i], bb[j], acc[i][j]);
        }
    }
    int row0 = blockIdx.y * 64 + ty * 4;
    int col0 = blockIdx.x * 64 + tx * 4;
    float4 bsv = *(const float4*)(bias + col0);
    float bb[4] = {bsv.x, bsv.y, bsv.z, bsv.w};
#pragma unroll
    for (int i = 0; i < 4; i++) {
        float* cp = C + (size_t)(row0 + i) * N + col0;
        float r[4];
#pragma unroll
        for (int j = 0; j < 4; j++) {
            float xv = acc[i][j] + bb[j];
            r[j] = fmaxf(xv, 0.f) + log1pf(expf(-fabsf(xv)));   // softplus
        }
        *(float4*)cp = make_float4(r[0], r[1], r[2], r[3]);
    }
}

// ---------------- selective scan, 3-phase chunked ----------------
// Thread = (b, chunk, d); all 16 s-states live in registers.
// Phase 1: per (b,d,chunk): P[s] = prod(exp(dv*A_s)), S[s] = chunk-local end state.
__global__ __launch_bounds__(256) void scan_chunk(const float* __restrict__ delta,
                                                  const float* __restrict__ a,
                                                  const float* __restrict__ bcd,
                                                  const float* __restrict__ A_log,
                                                  float* __restrict__ P, float* __restrict__ S) {
    int tid = threadIdx.x;
    int blk = blockIdx.x;                 // BATCH * NC * (DM/256)
    int dblk = blk % (DM / 256);
    int c = (blk / (DM / 256)) % NC;
    int b = blk / ((DM / 256) * NC);
    int d = dblk * 256 + tid;
    int t0 = b * SEQLEN + c * CL;

    __shared__ float LB[CL][16];          // B part of bcd for this chunk
    {
        int row = tid >> 4, col = tid & 15;   // 256 = CL*16 values
        LB[row][col] = bcd[(size_t)(t0 + row) * 128 + col];
    }
    __syncthreads();

    float An[16];
    {
        const float4* ap = (const float4*)(A_log + (size_t)d * 16);
#pragma unroll
        for (int q = 0; q < 4; q++) {
            float4 v = ap[q];
            An[q * 4 + 0] = -expf(v.x); An[q * 4 + 1] = -expf(v.y);
            An[q * 4 + 2] = -expf(v.z); An[q * 4 + 3] = -expf(v.w);
        }
    }
    float h[16], Pv[16];
#pragma unroll
    for (int s = 0; s < 16; s++) { h[s] = 0.f; Pv[s] = 1.f; }

    for (int l = 0; l < CL; l++) {
        int t = t0 + l;
        float dv = delta[(size_t)t * DM + d];
        float av = a[(size_t)t * DM + d];
        float dva = dv * av;
#pragma unroll
        for (int s = 0; s < 16; s++) {
            float e = expf(dv * An[s]);
            Pv[s] *= e;
            h[s] = fmaf(e, h[s], dva * LB[l][s]);
        }
    }
    size_t g0 = (size_t)c * NG + (size_t)(b * DM + d) * 16;
#pragma unroll
    for (int q = 0; q < 4; q++) {
        *(f32x4*)(P + g0 + q * 4) = (f32x4){Pv[q*4], Pv[q*4+1], Pv[q*4+2], Pv[q*4+3]};
        *(f32x4*)(S + g0 + q * 4) = (f32x4){h[q*4], h[q*4+1], h[q*4+2], h[q*4+3]};
    }
}

// Phase 2: serial combine over the NC chunk summaries -> h_init per chunk.
// Hb may alias P: P[c] is read before Hb[c] is written, same thread, same address.
__global__ __launch_bounds__(256) void scan_combine(const float* __restrict__ P,
                                                    const float* __restrict__ S,
                                                    float* __restrict__ Hb) {
    int g = blockIdx.x * 256 + threadIdx.x;
    float h = 0.f;
#pragma unroll
    for (int c = 0; c < NC; c++) {
        float Pv = P[c * NG + g];
        float Sv = S[c * NG + g];
        Hb[c * NG + g] = h;
        h = fmaf(Pv, h, Sv);
    }
}

// Phase 3: re-apply with correct h_init; fuse C-reduction (in-thread), D-skip, silu gate.
__global__ __launch_bounds__(256) void scan_apply(const float* __restrict__ delta,
                                                  const float* __restrict__ a,
                                                  const float* __restrict__ bcd,
                                                  const float* __restrict__ ab,
                                                  const float* __restrict__ A_log,
                                                  const float* __restrict__ Dp,
                                                  const float* __restrict__ Hb,
                                                  unsigned short* __restrict__ y1b) {
    int tid = threadIdx.x;
    int blk = blockIdx.x;
    int dblk = blk % (DM / 256);
    int c = (blk / (DM / 256)) % NC;
    int b = blk / ((DM / 256) * NC);
    int d = dblk * 256 + tid;
    int t0 = b * SEQLEN + c * CL;

    __shared__ float LB[CL][32];          // B (0..15) + C (16..31)
    {
        int row = tid >> 4, col = (tid & 15) * 2;   // 512 floats via float2
        *(float2*)&LB[row][col] = *(const float2*)&bcd[(size_t)(t0 + row) * 128 + col];
    }
    __syncthreads();

    float An[16];
    {
        const float4* ap = (const float4*)(A_log + (size_t)d * 16);
#pragma unroll
        for (int q = 0; q < 4; q++) {
            float4 v = ap[q];
            An[q * 4 + 0] = -expf(v.x); An[q * 4 + 1] = -expf(v.y);
            An[q * 4 + 2] = -expf(v.z); An[q * 4 + 3] = -expf(v.w);
        }
    }
    float Dv = Dp[d];
    float h[16];
    {
        const float* hp = Hb + (size_t)c * NG + (size_t)(b * DM + d) * 16;
#pragma unroll
        for (int q = 0; q < 4; q++) {
            float4 v = *(const float4*)(hp + q * 4);
            h[q * 4 + 0] = v.x; h[q * 4 + 1] = v.y; h[q * 4 + 2] = v.z; h[q * 4 + 3] = v.w;
        }
    }

    for (int l = 0; l < CL; l++) {
        int t = t0 + l;
        float dv = delta[(size_t)t * DM + d];
        float av = a[(size_t)t * DM + d];
        float dva = dv * av;
        float ct = 0.f;
#pragma unroll
        for (int s = 0; s < 16; s++) {
            float e = expf(dv * An[s]);
            h[s] = fmaf(e, h[s], dva * LB[l][s]);
            ct = fmaf(h[s], LB[l][16 + s], ct);
        }
        float bg = ab[(size_t)t * 2 * DM + DM + d];
        float sl = bg / (1.f + expf(-bg));
        float y = (ct + Dv * av) * sl;
        y1b[(size_t)t * DM + d] = f2bf(y);
    }
}

extern "C" void kernel_launch(void* const* d_in, const int* in_sizes, int n_in,
                              void* d_out, int out_size, void* d_ws, size_t ws_size,
                              hipStream_t stream) {
    const int* tok        = (const int*)d_in[0];
    const float* emb      = (const float*)d_in[1];
    const float* in_proj  = (const float*)d_in[2];   // (4, 3072, 768)
    const float* out_proj = (const float*)d_in[3];   // (4, 768, 1536)
    const float* sB       = (const float*)d_in[4];   // (4, 16, 1536)
    const float* sC       = (const float*)d_in[5];   // (4, 16, 1536)
    const float* sD0      = (const float*)d_in[6];   // (4, 96, 1536)
    const float* sD1      = (const float*)d_in[7];   // (4, 1536, 96)
    const float* sD1b     = (const float*)d_in[8];   // (4, 1536)
    const float* cw       = (const float*)d_in[9];   // (4, 1536, 4)
    const float* cb       = (const float*)d_in[10];  // (4, 1536)
    const float* A_log    = (const float*)d_in[11];  // (4, 1536, 16)
    const float* Dp       = (const float*)d_in[12];  // (4, 1536)
    const float* norm_w   = (const float*)d_in[13];  // (4, 768)
    const float* norm_f   = (const float*)d_in[14];  // (768,)
    const float* head_w   = (const float*)d_in[15];  // (32000, 768)
    float* out = (float*)d_out;

    char* base = (char*)d_ws;
    float* seq   = (float*)base;          base += (size_t)NTOK * DIN * 4;
    float* ab    = (float*)base;          base += (size_t)NTOK * 2 * DM * 4;
    float* ac    = (float*)base;          base += (size_t)NTOK * DM * 4;
    float* delta = (float*)base;          base += (size_t)NTOK * DM * 4;
    float* bcd   = (float*)base;          base += (size_t)NTOK * 128 * 4;
    unsigned short* xnb  = (unsigned short*)base;  base += (size_t)NTOK * DIN * 2;
    unsigned short* acb  = (unsigned short*)base;  base += (size_t)NTOK * DM * 2;
    unsigned short* y1b  = (unsigned short*)base;  base += (size_t)NTOK * DM * 2;
    float* P  = (float*)base;             base += (size_t)NG * NC * 4;   // Hb aliases P
    float* S  = (float*)base;             base += (size_t)NG * NC * 4;
    unsigned short* inpb  = (unsigned short*)base; base += (size_t)4 * 2 * DM * DIN * 2;
    unsigned short* outpb = (unsigned short*)base; base += (size_t)4 * DIN * DM * 2;
    unsigned short* wcatb = (unsigned short*)base; base += (size_t)4 * 128 * DM * 2;
    float* Hb = P;                        // in-place combine (read-before-write per thread)
    // head bf16 weights alias the (dead-by-then) ab+ac+delta region: 49.2 MB < 50.3 MB
    unsigned short* headb = (unsigned short*)ab;

    embed_kernel<<<NTOK, 192, 0, stream>>>(tok, emb, seq);
    wcat_kernel<<<4 * 128 * DM / 256, 256, 0, stream>>>(sB, sC, sD0, wcatb);
    cast_kernel<<<(4 * 2 * DM * DIN / 4 + 255) / 256, 256, 0, stream>>>(in_proj, inpb, 4 * 2 * DM * DIN / 4);
    cast_kernel<<<(4 * DIN * DM / 4 + 255) / 256, 256, 0, stream>>>(out_proj, outpb, 4 * DIN * DM / 4);

    for (int i = 0; i < 4; i++) {
        rmsnorm_kernel<<<NTOK, 256, 0, stream>>>(seq, norm_w + i * DIN, xnb);
        // in_proj: bf16 B, XCD-grouped (24 panels = 3/XCD)
        gemm_mfma<0, 1, 1><<<dim3(2 * DM / 128, NTOK / 128), 256, 0, stream>>>(
            xnb, inpb + (size_t)i * 2 * DM * DIN, ab, 2 * DM, DIN, 2 * DM / 128);
        conv_silu_kernel<<<NTOK * DM / 256, 256, 0, stream>>>(
            ab, cw + (size_t)i * DM * 4, cb + (size_t)i * DM, ac, acb);
        // bcd GEMM: 16 output blocks -> K-split x8 into zeroed buffer (128 blocks)
        zero_kernel<<<NTOK * 128 / 4 / 256, 256, 0, stream>>>(bcd, NTOK * 128 / 4);
        gemm_mfma<2, 8, 0><<<dim3(1, NTOK / 128, 8), 256, 0, stream>>>(
            acb, wcatb + (size_t)i * 128 * DM, bcd, 128, DM, 1);
        gemm32_softplus<<<dim3(DM / 64, NTOK / 64), 256, 0, stream>>>(
            bcd + 32, 128, sD1 + (size_t)i * DM * DD, delta, DM, DD, sD1b + (size_t)i * DM);
        scan_chunk<<<BATCH * NC * (DM / 256), 256, 0, stream>>>(
            delta, ac, bcd, A_log + (size_t)i * DM * DS, P, S);
        scan_combine<<<NG / 256, 256, 0, stream>>>(P, S, Hb);
        scan_apply<<<BATCH * NC * (DM / 256), 256, 0, stream>>>(
            delta, ac, bcd, ab, A_log + (size_t)i * DM * DS, Dp + (size_t)i * DM, Hb, y1b);
        // out_proj residual: bf16 B, K-split x4 (384 blocks), atomic accumulate into seq
        gemm_mfma<2, 4, 0><<<dim3(DIN / 128, NTOK / 128, 4), 256, 0, stream>>>(
            y1b, outpb + (size_t)i * DIN * DM, seq, DIN, DM, DIN / 128);
    }
    rmsnorm_kernel<<<NTOK, 256, 0, stream>>>(seq, norm_f, xnb);
    cast_kernel<<<(32000 * DIN / 4 + 255) / 256, 256, 0, stream>>>(head_w, headb, 32000 * DIN / 4);
    // head GEMM: bf16 B, XCD-grouped (250 panels padded to 256; 32/XCD)
    gemm_mfma<0, 1, 1><<<dim3(256, NTOK / 128), 256, 0, stream>>>(
        xnb, headb, out, 32000, DIN, 32000 / 128);
}